// Round 1
// baseline (117.267 us; speedup 1.0000x reference)
//
#include <hip/hip_runtime.h>

// FeatureEmbedder: out[b, f*64+d] = relu(x[b,f] * W[f,d] + b[f,d])
// x: [16384, 128] f32, W: [128, 64] f32, b: [128, 64] f32
// out: [16384, 8192] f32  (512 MB -> HBM-write-bound)

#define BATCH 16384
#define NFEAT 128
#define EMBD  64
// float4 view: 2048 float4 per output row (8192 f32 / 4), 16 float4 per feature
#define ROW4  (NFEAT * EMBD / 4)   // 2048
#define FEAT4 (EMBD / 4)           // 16

__global__ __launch_bounds__(256) void feature_embed_kernel(
    const float* __restrict__ x,
    const float4* __restrict__ W4,
    const float4* __restrict__ B4,
    float4* __restrict__ out4) {

    const int gtid = blockIdx.x * blockDim.x + threadIdx.x;  // 0 .. 524287
    const int col4 = gtid & (ROW4 - 1);   // loop-invariant column (float4 units)
    int row        = gtid >> 11;          // starting row, 0..255
    const int f    = col4 >> 4;           // feature index for this column

    // W/b are tiny (32 KB each) and column is fixed per thread -> hoist loads.
    const float4 w  = W4[col4];
    const float4 bb = B4[col4];
    const float* xp = x + f;

    #pragma unroll 4
    for (; row < BATCH; row += 256) {
        const float xv = xp[row << 7];    // x[row, f] (broadcast across 16 lanes)
        float4 o;
        o.x = fmaxf(fmaf(xv, w.x, bb.x), 0.0f);
        o.y = fmaxf(fmaf(xv, w.y, bb.y), 0.0f);
        o.z = fmaxf(fmaf(xv, w.z, bb.z), 0.0f);
        o.w = fmaxf(fmaf(xv, w.w, bb.w), 0.0f);
        out4[(row << 11) + col4] = o;     // 64 lanes x 16 B = 1 KB coalesced
    }
}

extern "C" void kernel_launch(void* const* d_in, const int* in_sizes, int n_in,
                              void* d_out, int out_size, void* d_ws, size_t ws_size,
                              hipStream_t stream) {
    const float*  x  = (const float*)d_in[0];
    const float4* W4 = (const float4*)d_in[1];
    const float4* B4 = (const float4*)d_in[2];
    float4* out4     = (float4*)d_out;

    // 2048 blocks x 256 threads = 524288 threads = 256 rows of float4s.
    // Grid stride is a multiple of the row width, so each thread's column
    // (and thus its W/b fragment) is fixed for the whole kernel.
    feature_embed_kernel<<<2048, 256, 0, stream>>>(x, W4, B4, out4);
}